// Round 7
// baseline (242.558 us; speedup 1.0000x reference)
//
#include <hip/hip_runtime.h>
#include <math.h>

#define Cc 256
#define NH 8
#define HD 32
#define Tt 256
#define MH 256
#define TBL 961  // 31*31 distinct relative offsets

typedef _Float16 f16;
typedef f16 f16x4 __attribute__((ext_vector_type(4)));
typedef f16 f16x8 __attribute__((ext_vector_type(8)));
typedef float f32x4 __attribute__((ext_vector_type(4)));

// stride-32 f16 rows, 16B-chunk XOR swizzle, key=(row>>2)&3.
__device__ __forceinline__ f16x8 ld8(const f16* base, int row, int kc) {
  return *(const f16x8*)&base[row * 32 + ((kc ^ ((row >> 2) & 3)) << 3)];
}
__device__ __forceinline__ void st8(f16* base, int row, int kc, f16x8 v) {
  *(f16x8*)&base[row * 32 + ((kc ^ ((row >> 2) & 3)) << 3)] = v;
}
__device__ __forceinline__ int sidx(int row, int col) {
  return row * 32 + (((col >> 3) ^ ((row >> 2) & 3)) << 3) + (col & 7);
}
// Vt: [d=32][t=256] stride 256, full 3-bit XOR: chunk ^= (d&7).
__device__ __forceinline__ int vsidx(int d, int t) {
  return d * 256 + (((t >> 3) ^ (d & 7)) << 3) + (t & 7);
}
__device__ __forceinline__ f16x8 vld8(const f16* base, int d, int tch) {
  return *(const f16x8*)&base[d * 256 + ((tch ^ (d & 7)) << 3)];
}

// ---------------------------------------------------------------------------
// Kernel 1 (stage0 = merged prep+xpose).
// Blocks 0..4095: transpose+convert x [B][C][T] fp32 -> xt [B][T][C] f16.
//   R12: tile chunk-XOR key changed (row&7) -> ((row>>2)&7).  Write-bank
//   audit: per instruction lanes l=0..15 write rows tl=4l+u; old key gave
//   bank = 16(l&1)+f(u,p) -> 8-way conflict.  New key = l&7 -> 16 distinct
//   banks (enumerated).  Reads use the same key; bijective per row;
//   b128 reads stay 16B-aligned and conflict-free.
// Blocks 4096..4103: bias-MLP table.  4104..4135: w_proj fp32->f16.
// 4136..4159: w_qkv gather.
// ---------------------------------------------------------------------------
__global__ __launch_bounds__(256) void stage0_kernel(
    const float* __restrict__ x, f16* __restrict__ xt,
    const float* __restrict__ mw1, const float* __restrict__ mb1,
    const float* __restrict__ mw2, const float* __restrict__ mb2,
    const float* __restrict__ w_proj, const float* __restrict__ w_qkv,
    float* __restrict__ table, float* __restrict__ tablemax,
    f16* __restrict__ wpf, f16* __restrict__ wqf) {
  __shared__ __align__(16) char smem0[9216];
  int tid = threadIdx.x;
  int blk = blockIdx.x;

  if (blk < 4096) {  // ---- xpose: 64x64 tile, float4 loads (G13)
    f16* tile = (f16*)smem0;  // [64][72] f16, 8-chunk XOR swizzle, key=(row>>2)&7
    int b = blk >> 4, ti = (blk >> 2) & 3, tj = blk & 3;
    const float* xb = x + (size_t)b * 65536;
    int t4 = (tid & 15) * 4, cg = tid >> 4;
#pragma unroll
    for (int p = 0; p < 4; p++) {
      int cl = cg + p * 16;
      float4 v = *(const float4*)&xb[(size_t)(ti * 64 + cl) * 256 + tj * 64 + t4];
      const float* vp = (const float*)&v;
#pragma unroll
      for (int u = 0; u < 4; u++) {
        int tl = t4 + u;
        tile[tl * 72 + (((cl >> 3) ^ ((tl >> 2) & 7)) << 3) + (cl & 7)] = (f16)vp[u];
      }
    }
    __syncthreads();
    f16* xtb = xt + (size_t)b * 65536;
    int tr = tid >> 3, ck = tid & 7;  // 8 lanes cover one 128B row segment
#pragma unroll
    for (int u = 0; u < 2; u++) {
      int r = tr + u * 32;
      f16x8 v = *(const f16x8*)&tile[r * 72 + ((ck ^ ((r >> 2) & 7)) << 3)];
      *(f16x8*)&xtb[(size_t)(tj * 64 + r) * 256 + ti * 64 + ck * 8] = v;
    }
    return;
  }

  blk -= 4096;
  if (blk >= NH + 32) {  // ---- w_qkv gather+convert: 768 rows x 32 chunks
    int blk2 = blk - NH - 32;  // 0..23
#pragma unroll
    for (int pass = 0; pass < 4; pass++) {
      int chunkid = blk2 * 256 + tid + pass * 6144;
      int row = chunkid >> 5, ck = chunkid & 31;  // row in [0,768)
      int hh = row / 96, n = row % 96;
      int srow = ((n >> 5) << 8) + (hh << 5) + (n & 31);
      const float* wp = w_qkv + (size_t)srow * Cc + ck * 8;
      f16x8 v;
#pragma unroll
      for (int u = 0; u < 8; u++) v[u] = (f16)wp[u];
      *(f16x8*)&wqf[(size_t)row * Cc + ck * 8] = v;
    }
    return;
  }
  if (blk >= NH) {  // ---- w_proj convert
    int base = (blk - NH) * 2048 + tid * 8;
    f16x8 v;
#pragma unroll
    for (int u = 0; u < 8; u++) v[u] = (f16)w_proj[base + u];
    *(f16x8*)&wpf[base] = v;
    return;
  }
  // ---- bias-MLP table for head `blk` (float4-packed weights, 4-entry ILP)
  float4* s_w = (float4*)smem0;              // [MH] {w1a, w1b, b1, w2}
  float* red = (float*)(smem0 + 4096);       // [256]
  for (int i = tid; i < MH; i += 256) {
    float4 w;
    w.x = mw1[2 * i];
    w.y = mw1[2 * i + 1];
    w.z = mb1[i];
    w.w = mw2[blk * MH + i];
    s_w[i] = w;
  }
  __syncthreads();
  float b2 = mb2[blk];
  float d0v[4], d1v[4], ov[4];
#pragma unroll
  for (int j = 0; j < 4; j++) {
    int idx = tid + j * 256;
    int ii = idx < TBL ? idx : TBL - 1;
    float fdi = (float)(ii / 31 - 15);
    float fdj = (float)(ii % 31 - 15);
    d0v[j] = (fdi > 0.f ? 1.f : (fdi < 0.f ? -1.f : 0.f)) * log1pf(fabsf(fdi));
    d1v[j] = (fdj > 0.f ? 1.f : (fdj < 0.f ? -1.f : 0.f)) * log1pf(fabsf(fdj));
    ov[j] = b2;
  }
  for (int m = 0; m < MH; m++) {
    float4 w = s_w[m];
#pragma unroll
    for (int j = 0; j < 4; j++) {
      float hid = fmaxf(fmaf(d0v[j], w.x, fmaf(d1v[j], w.y, w.z)), 0.f);
      ov[j] = fmaf(hid, w.w, ov[j]);
    }
  }
  float lmax = -1e30f;
#pragma unroll
  for (int j = 0; j < 4; j++) {
    int idx = tid + j * 256;
    if (idx < TBL) {
      table[blk * TBL + idx] = ov[j];
      lmax = fmaxf(lmax, ov[j]);
    }
  }
  red[tid] = lmax;
  __syncthreads();
  for (int s = 128; s > 0; s >>= 1) {
    if (tid < s) red[tid] = fmaxf(red[tid], red[tid + s]);
    __syncthreads();
  }
  if (tid == 0) tablemax[blk] = red[0];
}

// ---------------------------------------------------------------------------
// Kernel 2: fused QKV + cosine-sim attention, swapped-operand phase 2.
// Block = (b,h), 512 thr = 8 waves.  LDS 67328 B -> 2 blocks/CU.
// R6: chunked XCD swizzle.  R7: f16 xt/wqf staging (153->106).
// R8: swizzled normalize + setprio (106->92).  R9: ones-MFMA denominator +
// f16x4 V stores (91.5 us -- the best measured form; reverted to here).
// R10/R11 LESSON: occupancy is REGISTER-bound (~64 VGPR + ~64 AGPR = 128
// regs/wave -> 4 waves/SIMD -> 2 blocks/CU regardless of LDS), and
// e-serializing the P roundtrip lengthened the critical path 21%.  So: keep
// the parallel-e P + single lgkmcnt drain; don't chase LDS size.
// ---------------------------------------------------------------------------
__global__ __launch_bounds__(512, 4) void fused_attn(
    const f16* __restrict__ xt, const f16* __restrict__ wqf,
    const float* __restrict__ b_qkv, const float* __restrict__ table,
    const float* __restrict__ tablemax, const float* __restrict__ tau,
    f16* __restrict__ attnH) {
  __shared__ __align__(16) char smem[67328];
  f16* Qa = (f16*)smem;                    // 16384 B  (ph1: Xa; ph2: P w0..6)
  f16* Ka = (f16*)(smem + 16384);          // 16384 B  (ph1: Wa in first 6 KB)
  f16* Vt = (f16*)(smem + 32768);          // 16384 B
  f16* Pspare = (f16*)(smem + 49152);      // 2304 B   (wave 7's P)
  float* tbv = (float*)(smem + 51456);     // 31x32 float4 = 15872 B
  f16* Xa = (f16*)smem;
  f16* Wa = (f16*)(smem + 16384);

  int tid = threadIdx.x;
  int o = blockIdx.x;
  int bh = ((o & 7) << 8) | (o >> 3);  // chunked XCD swizzle (grid 2048 % 8 == 0)
  int b = bh >> 3, h = bh & 7;
  int wv = tid >> 6, ln = tid & 63, lq = ln >> 4, lm = ln & 15;

  const float LOG2E = 1.4426950408889634f;
  float rtau = 1.0f / fmaxf(tau[h], 0.01f);
  float tmaxh = tablemax[h];

  // tbv[di][c] = float4{ tb(c), tb(c-1), tb(c-2), tb(c-3) }, log2-domain,
  // pre-shifted.  Lane reads component r at dj = c0l - r.
  for (int idx = tid; idx < 31 * 32; idx += 512) {
    int di_ = idx >> 5, c = idx & 31;
    float4 v;
    float* vp = (float*)&v;
#pragma unroll
    for (int u = 0; u < 4; u++) {
      int dj = c - u;
      dj = dj < 0 ? 0 : (dj > 30 ? 30 : dj);
      vp[u] = (table[h * TBL + di_ * 31 + dj] - tmaxh - rtau * 1.0001f) * LOG2E;
    }
    *(float4*)&tbv[idx * 4] = v;
  }

  float bj[6];
#pragma unroll
  for (int nt = 0; nt < 6; nt++) {
    int n = nt * 16 + lm;
    int row = ((n >> 5) << 8) + (h << 5) + (n & 31);
    bj[nt] = b_qkv[row];
  }

  // ---- Phase 1: QKV GEMM, M=256 N=96 K=256, MFMA 16x16x32_f16
  const f16* xtb = xt + (size_t)b * 65536;
  const f16* wqh = wqf + (size_t)h * 24576;
  int xt_ = tid >> 1, xkc = (tid & 1) * 2;  // thread's X chunk pair
  int wn = tid >> 2, wck = tid & 3;         // thread's W chunk (tid<384)

  f32x4 acc[2][6] = {};
  f16x8 xv0, xv1, wvv;
  xv0 = *(const f16x8*)&xtb[xt_ * 256 + xkc * 8];
  xv1 = *(const f16x8*)&xtb[xt_ * 256 + xkc * 8 + 8];
  if (tid < 384) wvv = *(const f16x8*)&wqh[wn * 256 + wck * 8];

  for (int c0 = 0; c0 < Cc; c0 += 32) {
    st8(Xa, xt_, xkc, xv0);
    st8(Xa, xt_, xkc + 1, xv1);
    if (tid < 384) st8(Wa, wn, wck, wvv);
    __syncthreads();
    if (c0 + 32 < Cc) {  // prefetch next K-slice under the MFMAs
      xv0 = *(const f16x8*)&xtb[xt_ * 256 + c0 + 32 + xkc * 8];
      xv1 = *(const f16x8*)&xtb[xt_ * 256 + c0 + 32 + xkc * 8 + 8];
      if (tid < 384) wvv = *(const f16x8*)&wqh[wn * 256 + c0 + 32 + wck * 8];
    }
    f16x8 af[2], bf[6];
#pragma unroll
    for (int e = 0; e < 2; e++) af[e] = ld8(Xa, wv * 32 + e * 16 + lm, lq);
#pragma unroll
    for (int nt = 0; nt < 6; nt++) bf[nt] = ld8(Wa, nt * 16 + lm, lq);
#pragma unroll
    for (int e = 0; e < 2; e++)
#pragma unroll
      for (int nt = 0; nt < 6; nt++)
        acc[e][nt] = __builtin_amdgcn_mfma_f32_16x16x32_f16(af[e], bf[nt],
                                                            acc[e][nt], 0, 0, 0);
    __syncthreads();
  }

  // epilogue: + bias, scatter to Qa/Ka (t-major, scalar) and Vt (d-major f16x4)
#pragma unroll
  for (int e = 0; e < 2; e++) {
#pragma unroll
    for (int nt = 0; nt < 6; nt++) {
      int d = (nt & 1) * 16 + lm;
      if (nt < 4) {
#pragma unroll
        for (int r = 0; r < 4; r++) {
          int t = wv * 32 + e * 16 + lq * 4 + r;
          f16 v = (f16)(acc[e][nt][r] + bj[nt]);
          if (nt < 2) Qa[sidx(t, d)] = v;
          else        Ka[sidx(t, d)] = v;
        }
      } else {
        int t0 = wv * 32 + e * 16 + lq * 4;
        f16x4 pv;
#pragma unroll
        for (int r = 0; r < 4; r++) pv[r] = (f16)(acc[e][nt][r] + bj[nt]);
        *(f16x4*)&Vt[vsidx(d, t0)] = pv;
      }
    }
  }
  __syncthreads();

  // normalize Q,K rows in place (fold rtau*log2e into Q); swizzled chunks
  if (tid < 256) {
    int t = tid;
    float s = 0.f;
    f16x8 v[4];
#pragma unroll
    for (int ck = 0; ck < 4; ck++) {
      v[ck] = ld8(Qa, t, ck);
#pragma unroll
      for (int u = 0; u < 8; u++) { float f = (float)v[ck][u]; s = fmaf(f, f, s); }
    }
    float sc_ = rsqrtf(s) * rtau * LOG2E;
#pragma unroll
    for (int ck = 0; ck < 4; ck++) {
      f16x8 o2;
#pragma unroll
      for (int u = 0; u < 8; u++) o2[u] = (f16)((float)v[ck][u] * sc_);
      st8(Qa, t, ck, o2);
    }
  } else {
    int t = tid - 256;
    float s = 0.f;
    f16x8 v[4];
#pragma unroll
    for (int ck = 0; ck < 4; ck++) {
      v[ck] = ld8(Ka, t, ck);
#pragma unroll
      for (int u = 0; u < 8; u++) { float f = (float)v[ck][u]; s = fmaf(f, f, s); }
    }
    float sc_ = rsqrtf(s);
#pragma unroll
    for (int ck = 0; ck < 4; ck++) {
      f16x8 o2;
#pragma unroll
      for (int u = 0; u < 8; u++) o2[u] = (f16)((float)v[ck][u] * sc_);
      st8(Ka, t, ck, o2);
    }
  }
  __syncthreads();

  // hoist Q fragments (B-operand rows q = wv*32+e*16+lm), then Qa -> P space
  f16x8 qf[2];
#pragma unroll
  for (int e = 0; e < 2; e++) qf[e] = ld8(Qa, wv * 32 + e * 16 + lm, lq);
  __syncthreads();  // all waves done reading Qa before it becomes P

  f16* Pme = (wv < 7) ? (Qa + wv * 1152) : Pspare;  // 32 rows x stride 36 f16
  int c0l = lm - lq * 4 + 15;                        // lane-constant dj base
  const float4* tbp = (const float4*)tbv;
  f32x4 acco[2][2] = {};
  f32x4 acco_s[2] = {};  // ones-MFMA row sums (softmax denominator)
  f16x8 onev;
#pragma unroll
  for (int u = 0; u < 8; u++) onev[u] = (f16)1.0f;
  int dibase = wv * 2 + 15;

  // ---- Phase 2: S^T = mfma(K,Q) -> packed b64 P writes -> PV. No barriers.
  for (int n0 = 0; n0 < Tt; n0 += 32) {
    f16x8 kf[2];
#pragma unroll
    for (int nt = 0; nt < 2; nt++) kf[nt] = ld8(Ka, n0 + nt * 16 + lm, lq);
    f32x4 zero = {0.f, 0.f, 0.f, 0.f};
    f32x4 sc[2][2];
    __builtin_amdgcn_s_setprio(1);
#pragma unroll
    for (int e = 0; e < 2; e++)
#pragma unroll
      for (int nt = 0; nt < 2; nt++)
        sc[e][nt] = __builtin_amdgcn_mfma_f32_16x16x32_f16(kf[nt], qf[e], zero,
                                                           0, 0, 0);
    __builtin_amdgcn_s_setprio(0);
#pragma unroll
    for (int e = 0; e < 2; e++) {
#pragma unroll
      for (int nt = 0; nt < 2; nt++) {
        int di_ = dibase + e - (n0 >> 4) - nt;
        float4 bv = tbp[di_ * 32 + c0l];
        const float* bvp = (const float*)&bv;
        f16x4 pv;
#pragma unroll
        for (int r = 0; r < 4; r++) pv[r] = (f16)exp2f(sc[e][nt][r] + bvp[r]);
        *(f16x4*)&Pme[(e * 16 + lm) * 36 + nt * 16 + lq * 4] = pv;
      }
    }
    asm volatile("s_waitcnt lgkmcnt(0)" ::: "memory");
    f16x8 pf[2], vf[2];
#pragma unroll
    for (int e = 0; e < 2; e++) {
      f16x4 p0 = *(f16x4*)&Pme[(e * 16 + lm) * 36 + lq * 8];
      f16x4 p1 = *(f16x4*)&Pme[(e * 16 + lm) * 36 + lq * 8 + 4];
      pf[e] = __builtin_shufflevector(p0, p1, 0, 1, 2, 3, 4, 5, 6, 7);
    }
#pragma unroll
    for (int dt = 0; dt < 2; dt++)
      vf[dt] = vld8(Vt, dt * 16 + lm, (n0 >> 3) + lq);
    __builtin_amdgcn_s_setprio(1);
#pragma unroll
    for (int e = 0; e < 2; e++) {
#pragma unroll
      for (int dt = 0; dt < 2; dt++)
        acco[e][dt] = __builtin_amdgcn_mfma_f32_16x16x32_f16(pf[e], vf[dt],
                                                             acco[e][dt], 0, 0, 0);
      acco_s[e] = __builtin_amdgcn_mfma_f32_16x16x32_f16(pf[e], onev,
                                                         acco_s[e], 0, 0, 0);
    }
    __builtin_amdgcn_s_setprio(0);
  }

  // acco_s[e][r] = sum_n P[q][n] for exactly this thread's epilogue rows.
#pragma unroll
  for (int e = 0; e < 2; e++)
#pragma unroll
    for (int r = 0; r < 4; r++) {
      float rl = __builtin_amdgcn_rcpf(acco_s[e][r]);
      int q = wv * 32 + e * 16 + lq * 4 + r;
#pragma unroll
      for (int dt = 0; dt < 2; dt++) {
        int d = dt * 16 + lm;
        attnH[((size_t)b * Tt + q) * Cc + h * HD + d] =
            (f16)(acco[e][dt][r] * rl);
      }
    }
}

// ---------------------------------------------------------------------------
// Kernel 3: MFMA proj GEMM, coalesced staging.  A fp16 [B*T][256] x Wf fp16
// [256][256] -> out[b][c][t].  K-step 64 (128B row segments), stride-72 LDS,
// 37.4 KB -> 4 blocks/CU.
// ---------------------------------------------------------------------------
__global__ __launch_bounds__(256, 4) void proj_gemm(
    const f16* __restrict__ A, const f16* __restrict__ wf,
    const float* __restrict__ bp, float* __restrict__ out) {
  __shared__ __align__(16) f16 Af[128 * 72];   // 18432 B
  __shared__ __align__(16) f16 Wsh[128 * 72];  // 18432 B
  __shared__ float sB[128];
  int tid = threadIdx.x;
  int row0 = blockIdx.x * 128;
  int n0g = blockIdx.y * 128;
  int b = row0 >> 8, t0 = row0 & 255;
  int wv = tid >> 6, ln = tid & 63, lq = ln >> 4, lm = ln & 15;
  int cw = (wv & 1) * 64, tw = (wv >> 1) * 64;

  if (tid < 128) sB[tid] = bp[n0g + tid];

  f32x4 acc[4][4] = {};
  for (int k0 = 0; k0 < Cc; k0 += 64) {
#pragma unroll
    for (int p = 0; p < 4; p++) {
      int idx = p * 256 + tid;
      int row = idx >> 3, ch = idx & 7;
      f16x8 v = *(const f16x8*)&A[(size_t)(row0 + row) * Cc + k0 + ch * 8];
      *(f16x8*)&Af[row * 72 + ch * 8] = v;
    }
#pragma unroll
    for (int p = 0; p < 4; p++) {
      int idx = p * 256 + tid;
      int row = idx >> 3, ch = idx & 7;
      f16x8 v = *(const f16x8*)&wf[(size_t)(n0g + row) * Cc + k0 + ch * 8];
      *(f16x8*)&Wsh[row * 72 + ch * 8] = v;
    }
    __syncthreads();
#pragma unroll
    for (int kk = 0; kk < 2; kk++) {
      f16x8 wfr[4], af[4];
#pragma unroll
      for (int i = 0; i < 4; i++)
        wfr[i] = *(f16x8*)&Wsh[(cw + i * 16 + lm) * 72 + (kk * 4 + lq) * 8];
#pragma unroll
      for (int j = 0; j < 4; j++)
        af[j] = *(f16x8*)&Af[(tw + j * 16 + lm) * 72 + (kk * 4 + lq) * 8];
#pragma unroll
      for (int i = 0; i < 4; i++)
#pragma unroll
        for (int j = 0; j < 4; j++)
          acc[i][j] = __builtin_amdgcn_mfma_f32_16x16x32_f16(wfr[i], af[j],
                                                             acc[i][j], 0, 0, 0);
    }
    __syncthreads();
  }

  // epilogue: D[c][t], col = t -> coalesced stores
#pragma unroll
  for (int i = 0; i < 4; i++)
#pragma unroll
    for (int r = 0; r < 4; r++) {
      int crl = cw + i * 16 + lq * 4 + r;
      float bias = sB[crl];
#pragma unroll
      for (int j = 0; j < 4; j++) {
        int tcl = tw + j * 16 + lm;
        out[(size_t)b * 65536 + (size_t)(n0g + crl) * 256 + t0 + tcl] =
            acc[i][j][r] + bias;
      }
    }
}

// ---------------------------------------------------------------------------
extern "C" void kernel_launch(void* const* d_in, const int* in_sizes, int n_in,
                              void* d_out, int out_size, void* d_ws,
                              size_t ws_size, hipStream_t stream) {
  const float* x = (const float*)d_in[0];
  const float* w_qkv = (const float*)d_in[1];
  const float* b_qkv = (const float*)d_in[2];
  const float* w_proj = (const float*)d_in[3];
  const float* b_proj = (const float*)d_in[4];
  const float* mw1 = (const float*)d_in[5];
  const float* mb1 = (const float*)d_in[6];
  const float* mw2 = (const float*)d_in[7];
  const float* mb2 = (const float*)d_in[8];
  const float* tau = (const float*)d_in[9];
  float* out = (float*)d_out;

  const size_t NEEDED = (size_t)(TBL * NH + NH) * 4 + (size_t)65536 * 2 +
                        (size_t)256 * NH * Tt * HD * 2;
  if (ws_size < NEEDED) return;

  float* table = (float*)d_ws;
  float* tablemax = table + TBL * NH;
  f16* wpf = (f16*)(tablemax + NH);
  f16* attnH = wpf + 65536;

  // Stash f16 intermediates in d_out (64 MB fp32): xt = 33.5 MB, wqf = 384 KB.
  // proj_gemm fully overwrites d_out afterwards (stream-ordered).
  f16* xt = (f16*)d_out;
  f16* wqf = (f16*)d_out + (size_t)256 * 65536;

  stage0_kernel<<<4160, 256, 0, stream>>>(x, xt, mw1, mb1, mw2, mb2, w_proj,
                                          w_qkv, table, tablemax, wpf, wqf);
  fused_attn<<<256 * NH, 512, 0, stream>>>(xt, wqf, b_qkv, table, tablemax,
                                           tau, attnH);
  dim3 g3(512, 2);
  proj_gemm<<<g3, 256, 0, stream>>>(attnH, wpf, b_proj, out);
}

// Round 8
// 240.662 us; speedup vs baseline: 1.0079x; 1.0079x over previous
//
#include <hip/hip_runtime.h>
#include <math.h>

#define Cc 256
#define NH 8
#define HD 32
#define Tt 256
#define MH 256
#define TBL 961  // 31*31 distinct relative offsets

typedef _Float16 f16;
typedef f16 f16x4 __attribute__((ext_vector_type(4)));
typedef f16 f16x8 __attribute__((ext_vector_type(8)));
typedef float f32x4 __attribute__((ext_vector_type(4)));

// stride-32 f16 rows, 16B-chunk XOR swizzle, key=(row>>2)&3.
__device__ __forceinline__ f16x8 ld8(const f16* base, int row, int kc) {
  return *(const f16x8*)&base[row * 32 + ((kc ^ ((row >> 2) & 3)) << 3)];
}
__device__ __forceinline__ void st8(f16* base, int row, int kc, f16x8 v) {
  *(f16x8*)&base[row * 32 + ((kc ^ ((row >> 2) & 3)) << 3)] = v;
}
__device__ __forceinline__ int sidx(int row, int col) {
  return row * 32 + (((col >> 3) ^ ((row >> 2) & 3)) << 3) + (col & 7);
}
// Vt: [d=32][t=256] stride 256, full 3-bit XOR: chunk ^= (d&7).
__device__ __forceinline__ int vsidx(int d, int t) {
  return d * 256 + (((t >> 3) ^ (d & 7)) << 3) + (t & 7);
}
__device__ __forceinline__ f16x8 vld8(const f16* base, int d, int tch) {
  return *(const f16x8*)&base[d * 256 + ((tch ^ (d & 7)) << 3)];
}

// ---------------------------------------------------------------------------
// Kernel 1 (stage0 = merged prep+xpose).
// Blocks 0..4095: transpose+convert x [B][C][T] fp32 -> xt [B][T][C] f16.
// Blocks 4096..4103: bias-MLP table.  4104..4135: w_proj fp32->f16.
// 4136..4159: w_qkv gather.
// ---------------------------------------------------------------------------
__global__ __launch_bounds__(256) void stage0_kernel(
    const float* __restrict__ x, f16* __restrict__ xt,
    const float* __restrict__ mw1, const float* __restrict__ mb1,
    const float* __restrict__ mw2, const float* __restrict__ mb2,
    const float* __restrict__ w_proj, const float* __restrict__ w_qkv,
    float* __restrict__ table, float* __restrict__ tablemax,
    f16* __restrict__ wpf, f16* __restrict__ wqf) {
  __shared__ __align__(16) char smem0[9216];
  int tid = threadIdx.x;
  int blk = blockIdx.x;

  if (blk < 4096) {  // ---- xpose: 64x64 tile, float4 loads (G13)
    f16* tile = (f16*)smem0;  // [64][72] f16, 8-chunk XOR swizzle, key=(row>>2)&7
    int b = blk >> 4, ti = (blk >> 2) & 3, tj = blk & 3;
    const float* xb = x + (size_t)b * 65536;
    int t4 = (tid & 15) * 4, cg = tid >> 4;
#pragma unroll
    for (int p = 0; p < 4; p++) {
      int cl = cg + p * 16;
      float4 v = *(const float4*)&xb[(size_t)(ti * 64 + cl) * 256 + tj * 64 + t4];
      const float* vp = (const float*)&v;
#pragma unroll
      for (int u = 0; u < 4; u++) {
        int tl = t4 + u;
        tile[tl * 72 + (((cl >> 3) ^ ((tl >> 2) & 7)) << 3) + (cl & 7)] = (f16)vp[u];
      }
    }
    __syncthreads();
    f16* xtb = xt + (size_t)b * 65536;
    int tr = tid >> 3, ck = tid & 7;  // 8 lanes cover one 128B row segment
#pragma unroll
    for (int u = 0; u < 2; u++) {
      int r = tr + u * 32;
      f16x8 v = *(const f16x8*)&tile[r * 72 + ((ck ^ ((r >> 2) & 7)) << 3)];
      *(f16x8*)&xtb[(size_t)(tj * 64 + r) * 256 + ti * 64 + ck * 8] = v;
    }
    return;
  }

  blk -= 4096;
  if (blk >= NH + 32) {  // ---- w_qkv gather+convert: 768 rows x 32 chunks
    int blk2 = blk - NH - 32;  // 0..23
#pragma unroll
    for (int pass = 0; pass < 4; pass++) {
      int chunkid = blk2 * 256 + tid + pass * 6144;
      int row = chunkid >> 5, ck = chunkid & 31;  // row in [0,768)
      int hh = row / 96, n = row % 96;
      int srow = ((n >> 5) << 8) + (hh << 5) + (n & 31);
      const float* wp = w_qkv + (size_t)srow * Cc + ck * 8;
      f16x8 v;
#pragma unroll
      for (int u = 0; u < 8; u++) v[u] = (f16)wp[u];
      *(f16x8*)&wqf[(size_t)row * Cc + ck * 8] = v;
    }
    return;
  }
  if (blk >= NH) {  // ---- w_proj convert
    int base = (blk - NH) * 2048 + tid * 8;
    f16x8 v;
#pragma unroll
    for (int u = 0; u < 8; u++) v[u] = (f16)w_proj[base + u];
    *(f16x8*)&wpf[base] = v;
    return;
  }
  // ---- bias-MLP table for head `blk` (float4-packed weights, 4-entry ILP)
  float4* s_w = (float4*)smem0;              // [MH] {w1a, w1b, b1, w2}
  float* red = (float*)(smem0 + 4096);       // [256]
  for (int i = tid; i < MH; i += 256) {
    float4 w;
    w.x = mw1[2 * i];
    w.y = mw1[2 * i + 1];
    w.z = mb1[i];
    w.w = mw2[blk * MH + i];
    s_w[i] = w;
  }
  __syncthreads();
  float b2 = mb2[blk];
  float d0v[4], d1v[4], ov[4];
#pragma unroll
  for (int j = 0; j < 4; j++) {
    int idx = tid + j * 256;
    int ii = idx < TBL ? idx : TBL - 1;
    float fdi = (float)(ii / 31 - 15);
    float fdj = (float)(ii % 31 - 15);
    d0v[j] = (fdi > 0.f ? 1.f : (fdi < 0.f ? -1.f : 0.f)) * log1pf(fabsf(fdi));
    d1v[j] = (fdj > 0.f ? 1.f : (fdj < 0.f ? -1.f : 0.f)) * log1pf(fabsf(fdj));
    ov[j] = b2;
  }
  for (int m = 0; m < MH; m++) {
    float4 w = s_w[m];
#pragma unroll
    for (int j = 0; j < 4; j++) {
      float hid = fmaxf(fmaf(d0v[j], w.x, fmaf(d1v[j], w.y, w.z)), 0.f);
      ov[j] = fmaf(hid, w.w, ov[j]);
    }
  }
  float lmax = -1e30f;
#pragma unroll
  for (int j = 0; j < 4; j++) {
    int idx = tid + j * 256;
    if (idx < TBL) {
      table[blk * TBL + idx] = ov[j];
      lmax = fmaxf(lmax, ov[j]);
    }
  }
  red[tid] = lmax;
  __syncthreads();
  for (int s = 128; s > 0; s >>= 1) {
    if (tid < s) red[tid] = fmaxf(red[tid], red[tid + s]);
    __syncthreads();
  }
  if (tid == 0) tablemax[blk] = red[0];
}

// ---------------------------------------------------------------------------
// Kernel 2: fused QKV + cosine-sim attention, swapped-operand phase 2.
// Block = (b,h), 512 thr = 8 waves.  LDS 67328 B.
// R6: chunked XCD swizzle.  R7: f16 xt/wqf staging.  R8: swizzled normalize
// + setprio.  R9: ones-MFMA denominator + f16x4 V stores.
// R10/R11 LESSON: occupancy is register-bound (128 regs -> 16 waves/CU);
// don't chase LDS size.  R13 LESSON: cross-session clock variance ~18% --
// judge by within-run ratios only.
// R13 (this round): software-pipelined phase 2.  P(i) is written at the END
// of iteration i-1; iteration i runs QK(i+1) -> read P(i)/V(i) -> PV(i) ->
// exp/write P(i+1).  The hard `lgkmcnt(0)` drain after P-writes is GONE:
// writes retire under the QK MFMA cluster; same-wave in-order DS execution
// gives cross-lane RAW/WAR; zero-cost `asm ::: "memory"` fences stop the
// compiler reordering DS ops whose per-thread ranges look disjoint.
// ---------------------------------------------------------------------------
__global__ __launch_bounds__(512, 4) void fused_attn(
    const f16* __restrict__ xt, const f16* __restrict__ wqf,
    const float* __restrict__ b_qkv, const float* __restrict__ table,
    const float* __restrict__ tablemax, const float* __restrict__ tau,
    f16* __restrict__ attnH) {
  __shared__ __align__(16) char smem[67328];
  f16* Qa = (f16*)smem;                    // 16384 B  (ph1: Xa; ph2: P w0..6)
  f16* Ka = (f16*)(smem + 16384);          // 16384 B  (ph1: Wa in first 6 KB)
  f16* Vt = (f16*)(smem + 32768);          // 16384 B
  f16* Pspare = (f16*)(smem + 49152);      // 2304 B   (wave 7's P)
  float* tbv = (float*)(smem + 51456);     // 31x32 float4 = 15872 B
  f16* Xa = (f16*)smem;
  f16* Wa = (f16*)(smem + 16384);

  int tid = threadIdx.x;
  int o = blockIdx.x;
  int bh = ((o & 7) << 8) | (o >> 3);  // chunked XCD swizzle (grid 2048 % 8 == 0)
  int b = bh >> 3, h = bh & 7;
  int wv = tid >> 6, ln = tid & 63, lq = ln >> 4, lm = ln & 15;

  const float LOG2E = 1.4426950408889634f;
  float rtau = 1.0f / fmaxf(tau[h], 0.01f);
  float tmaxh = tablemax[h];

  // tbv[di][c] = float4{ tb(c), tb(c-1), tb(c-2), tb(c-3) }, log2-domain,
  // pre-shifted.  Lane reads component r at dj = c0l - r.
  for (int idx = tid; idx < 31 * 32; idx += 512) {
    int di_ = idx >> 5, c = idx & 31;
    float4 v;
    float* vp = (float*)&v;
#pragma unroll
    for (int u = 0; u < 4; u++) {
      int dj = c - u;
      dj = dj < 0 ? 0 : (dj > 30 ? 30 : dj);
      vp[u] = (table[h * TBL + di_ * 31 + dj] - tmaxh - rtau * 1.0001f) * LOG2E;
    }
    *(float4*)&tbv[idx * 4] = v;
  }

  float bj[6];
#pragma unroll
  for (int nt = 0; nt < 6; nt++) {
    int n = nt * 16 + lm;
    int row = ((n >> 5) << 8) + (h << 5) + (n & 31);
    bj[nt] = b_qkv[row];
  }

  // ---- Phase 1: QKV GEMM, M=256 N=96 K=256, MFMA 16x16x32_f16
  const f16* xtb = xt + (size_t)b * 65536;
  const f16* wqh = wqf + (size_t)h * 24576;
  int xt_ = tid >> 1, xkc = (tid & 1) * 2;  // thread's X chunk pair
  int wn = tid >> 2, wck = tid & 3;         // thread's W chunk (tid<384)

  f32x4 acc[2][6] = {};
  f16x8 xv0, xv1, wvv;
  xv0 = *(const f16x8*)&xtb[xt_ * 256 + xkc * 8];
  xv1 = *(const f16x8*)&xtb[xt_ * 256 + xkc * 8 + 8];
  if (tid < 384) wvv = *(const f16x8*)&wqh[wn * 256 + wck * 8];

  for (int c0 = 0; c0 < Cc; c0 += 32) {
    st8(Xa, xt_, xkc, xv0);
    st8(Xa, xt_, xkc + 1, xv1);
    if (tid < 384) st8(Wa, wn, wck, wvv);
    __syncthreads();
    if (c0 + 32 < Cc) {  // prefetch next K-slice under the MFMAs
      xv0 = *(const f16x8*)&xtb[xt_ * 256 + c0 + 32 + xkc * 8];
      xv1 = *(const f16x8*)&xtb[xt_ * 256 + c0 + 32 + xkc * 8 + 8];
      if (tid < 384) wvv = *(const f16x8*)&wqh[wn * 256 + c0 + 32 + wck * 8];
    }
    f16x8 af[2], bf[6];
#pragma unroll
    for (int e = 0; e < 2; e++) af[e] = ld8(Xa, wv * 32 + e * 16 + lm, lq);
#pragma unroll
    for (int nt = 0; nt < 6; nt++) bf[nt] = ld8(Wa, nt * 16 + lm, lq);
#pragma unroll
    for (int e = 0; e < 2; e++)
#pragma unroll
      for (int nt = 0; nt < 6; nt++)
        acc[e][nt] = __builtin_amdgcn_mfma_f32_16x16x32_f16(af[e], bf[nt],
                                                            acc[e][nt], 0, 0, 0);
    __syncthreads();
  }

  // epilogue: + bias, scatter to Qa/Ka (t-major, scalar) and Vt (d-major f16x4)
#pragma unroll
  for (int e = 0; e < 2; e++) {
#pragma unroll
    for (int nt = 0; nt < 6; nt++) {
      int d = (nt & 1) * 16 + lm;
      if (nt < 4) {
#pragma unroll
        for (int r = 0; r < 4; r++) {
          int t = wv * 32 + e * 16 + lq * 4 + r;
          f16 v = (f16)(acc[e][nt][r] + bj[nt]);
          if (nt < 2) Qa[sidx(t, d)] = v;
          else        Ka[sidx(t, d)] = v;
        }
      } else {
        int t0 = wv * 32 + e * 16 + lq * 4;
        f16x4 pv;
#pragma unroll
        for (int r = 0; r < 4; r++) pv[r] = (f16)(acc[e][nt][r] + bj[nt]);
        *(f16x4*)&Vt[vsidx(d, t0)] = pv;
      }
    }
  }
  __syncthreads();

  // normalize Q,K rows in place (fold rtau*log2e into Q); swizzled chunks
  if (tid < 256) {
    int t = tid;
    float s = 0.f;
    f16x8 v[4];
#pragma unroll
    for (int ck = 0; ck < 4; ck++) {
      v[ck] = ld8(Qa, t, ck);
#pragma unroll
      for (int u = 0; u < 8; u++) { float f = (float)v[ck][u]; s = fmaf(f, f, s); }
    }
    float sc_ = rsqrtf(s) * rtau * LOG2E;
#pragma unroll
    for (int ck = 0; ck < 4; ck++) {
      f16x8 o2;
#pragma unroll
      for (int u = 0; u < 8; u++) o2[u] = (f16)((float)v[ck][u] * sc_);
      st8(Qa, t, ck, o2);
    }
  } else {
    int t = tid - 256;
    float s = 0.f;
    f16x8 v[4];
#pragma unroll
    for (int ck = 0; ck < 4; ck++) {
      v[ck] = ld8(Ka, t, ck);
#pragma unroll
      for (int u = 0; u < 8; u++) { float f = (float)v[ck][u]; s = fmaf(f, f, s); }
    }
    float sc_ = rsqrtf(s);
#pragma unroll
    for (int ck = 0; ck < 4; ck++) {
      f16x8 o2;
#pragma unroll
      for (int u = 0; u < 8; u++) o2[u] = (f16)((float)v[ck][u] * sc_);
      st8(Ka, t, ck, o2);
    }
  }
  __syncthreads();

  // hoist Q fragments (B-operand rows q = wv*32+e*16+lm), then Qa -> P space
  f16x8 qf[2];
#pragma unroll
  for (int e = 0; e < 2; e++) qf[e] = ld8(Qa, wv * 32 + e * 16 + lm, lq);
  __syncthreads();  // all waves done reading Qa before it becomes P

  f16* Pme = (wv < 7) ? (Qa + wv * 1152) : Pspare;  // 32 rows x stride 36 f16
  int c0l = lm - lq * 4 + 15;                        // lane-constant dj base
  const float4* tbp = (const float4*)tbv;
  f32x4 acco[2][2] = {};
  f32x4 acco_s[2] = {};  // ones-MFMA row sums (softmax denominator)
  f16x8 onev;
#pragma unroll
  for (int u = 0; u < 8; u++) onev[u] = (f16)1.0f;
  int dibase = wv * 2 + 15;
  f32x4 zero = {0.f, 0.f, 0.f, 0.f};

  // ---- Phase 2, software-pipelined: P(i) written at end of iter i-1.
  // preamble: QK(0) -> exp -> write P(0)
  {
    f16x8 kf[2];
#pragma unroll
    for (int nt = 0; nt < 2; nt++) kf[nt] = ld8(Ka, nt * 16 + lm, lq);
    f32x4 sc[2][2];
    __builtin_amdgcn_s_setprio(1);
#pragma unroll
    for (int e = 0; e < 2; e++)
#pragma unroll
      for (int nt = 0; nt < 2; nt++)
        sc[e][nt] = __builtin_amdgcn_mfma_f32_16x16x32_f16(kf[nt], qf[e], zero,
                                                           0, 0, 0);
    __builtin_amdgcn_s_setprio(0);
#pragma unroll
    for (int e = 0; e < 2; e++)
#pragma unroll
      for (int nt = 0; nt < 2; nt++) {
        int di_ = dibase + e - nt;
        float4 bv = tbp[di_ * 32 + c0l];
        const float* bvp = (const float*)&bv;
        f16x4 pv;
#pragma unroll
        for (int r = 0; r < 4; r++) pv[r] = (f16)exp2f(sc[e][nt][r] + bvp[r]);
        *(f16x4*)&Pme[(e * 16 + lm) * 36 + nt * 16 + lq * 4] = pv;
      }
    asm volatile("" ::: "memory");  // compiler fence: no DS reorder past writes
  }

  for (int n0 = 0; n0 < Tt; n0 += 32) {
    int nn = n0 + 32;
    f32x4 sc[2][2];
    if (nn < Tt) {  // QK(i+1): its MFMAs cover P(i)'s write latency
      f16x8 kf[2];
#pragma unroll
      for (int nt = 0; nt < 2; nt++) kf[nt] = ld8(Ka, nn + nt * 16 + lm, lq);
      __builtin_amdgcn_s_setprio(1);
#pragma unroll
      for (int e = 0; e < 2; e++)
#pragma unroll
        for (int nt = 0; nt < 2; nt++)
          sc[e][nt] = __builtin_amdgcn_mfma_f32_16x16x32_f16(kf[nt], qf[e],
                                                             zero, 0, 0, 0);
      __builtin_amdgcn_s_setprio(0);
    }
    // read P(i) (writes retired under the QK cluster; same-wave DS in-order)
    f16x8 pf[2], vf[2];
#pragma unroll
    for (int e = 0; e < 2; e++) {
      f16x4 p0 = *(f16x4*)&Pme[(e * 16 + lm) * 36 + lq * 8];
      f16x4 p1 = *(f16x4*)&Pme[(e * 16 + lm) * 36 + lq * 8 + 4];
      pf[e] = __builtin_shufflevector(p0, p1, 0, 1, 2, 3, 4, 5, 6, 7);
    }
#pragma unroll
    for (int dt = 0; dt < 2; dt++)
      vf[dt] = vld8(Vt, dt * 16 + lm, (n0 >> 3) + lq);
    asm volatile("" ::: "memory");  // fence: P(i+1) writes can't hoist above
    __builtin_amdgcn_s_setprio(1);
#pragma unroll
    for (int e = 0; e < 2; e++) {
#pragma unroll
      for (int dt = 0; dt < 2; dt++)
        acco[e][dt] = __builtin_amdgcn_mfma_f32_16x16x32_f16(pf[e], vf[dt],
                                                             acco[e][dt], 0, 0, 0);
      acco_s[e] = __builtin_amdgcn_mfma_f32_16x16x32_f16(pf[e], onev,
                                                         acco_s[e], 0, 0, 0);
    }
    __builtin_amdgcn_s_setprio(0);
    if (nn < Tt) {  // exp + write P(i+1), overlapped with PV's MFMA tail
#pragma unroll
      for (int e = 0; e < 2; e++)
#pragma unroll
        for (int nt = 0; nt < 2; nt++) {
          int di_ = dibase + e - (nn >> 4) - nt;
          float4 bv = tbp[di_ * 32 + c0l];
          const float* bvp = (const float*)&bv;
          f16x4 pv;
#pragma unroll
          for (int r = 0; r < 4; r++) pv[r] = (f16)exp2f(sc[e][nt][r] + bvp[r]);
          *(f16x4*)&Pme[(e * 16 + lm) * 36 + nt * 16 + lq * 4] = pv;
        }
      asm volatile("" ::: "memory");  // fence before next iter's reads
    }
  }

  // acco_s[e][r] = sum_n P[q][n] for exactly this thread's epilogue rows.
#pragma unroll
  for (int e = 0; e < 2; e++)
#pragma unroll
    for (int r = 0; r < 4; r++) {
      float rl = __builtin_amdgcn_rcpf(acco_s[e][r]);
      int q = wv * 32 + e * 16 + lq * 4 + r;
#pragma unroll
      for (int dt = 0; dt < 2; dt++) {
        int d = dt * 16 + lm;
        attnH[((size_t)b * Tt + q) * Cc + h * HD + d] =
            (f16)(acco[e][dt][r] * rl);
      }
    }
}

// ---------------------------------------------------------------------------
// Kernel 3: MFMA proj GEMM, coalesced staging.  A fp16 [B*T][256] x Wf fp16
// [256][256] -> out[b][c][t].  K-step 64 (128B row segments), stride-72 LDS,
// 37.4 KB -> 4 blocks/CU.
// ---------------------------------------------------------------------------
__global__ __launch_bounds__(256, 4) void proj_gemm(
    const f16* __restrict__ A, const f16* __restrict__ wf,
    const float* __restrict__ bp, float* __restrict__ out) {
  __shared__ __align__(16) f16 Af[128 * 72];   // 18432 B
  __shared__ __align__(16) f16 Wsh[128 * 72];  // 18432 B
  __shared__ float sB[128];
  int tid = threadIdx.x;
  int row0 = blockIdx.x * 128;
  int n0g = blockIdx.y * 128;
  int b = row0 >> 8, t0 = row0 & 255;
  int wv = tid >> 6, ln = tid & 63, lq = ln >> 4, lm = ln & 15;
  int cw = (wv & 1) * 64, tw = (wv >> 1) * 64;

  if (tid < 128) sB[tid] = bp[n0g + tid];

  f32x4 acc[4][4] = {};
  for (int k0 = 0; k0 < Cc; k0 += 64) {
#pragma unroll
    for (int p = 0; p < 4; p++) {
      int idx = p * 256 + tid;
      int row = idx >> 3, ch = idx & 7;
      f16x8 v = *(const f16x8*)&A[(size_t)(row0 + row) * Cc + k0 + ch * 8];
      *(f16x8*)&Af[row * 72 + ch * 8] = v;
    }
#pragma unroll
    for (int p = 0; p < 4; p++) {
      int idx = p * 256 + tid;
      int row = idx >> 3, ch = idx & 7;
      f16x8 v = *(const f16x8*)&wf[(size_t)(n0g + row) * Cc + k0 + ch * 8];
      *(f16x8*)&Wsh[row * 72 + ch * 8] = v;
    }
    __syncthreads();
#pragma unroll
    for (int kk = 0; kk < 2; kk++) {
      f16x8 wfr[4], af[4];
#pragma unroll
      for (int i = 0; i < 4; i++)
        wfr[i] = *(f16x8*)&Wsh[(cw + i * 16 + lm) * 72 + (kk * 4 + lq) * 8];
#pragma unroll
      for (int j = 0; j < 4; j++)
        af[j] = *(f16x8*)&Af[(tw + j * 16 + lm) * 72 + (kk * 4 + lq) * 8];
#pragma unroll
      for (int i = 0; i < 4; i++)
#pragma unroll
        for (int j = 0; j < 4; j++)
          acc[i][j] = __builtin_amdgcn_mfma_f32_16x16x32_f16(wfr[i], af[j],
                                                             acc[i][j], 0, 0, 0);
    }
    __syncthreads();
  }

  // epilogue: D[c][t], col = t -> coalesced stores
#pragma unroll
  for (int i = 0; i < 4; i++)
#pragma unroll
    for (int r = 0; r < 4; r++) {
      int crl = cw + i * 16 + lq * 4 + r;
      float bias = sB[crl];
#pragma unroll
      for (int j = 0; j < 4; j++) {
        int tcl = tw + j * 16 + lm;
        out[(size_t)b * 65536 + (size_t)(n0g + crl) * 256 + t0 + tcl] =
            acc[i][j][r] + bias;
      }
    }
}

// ---------------------------------------------------------------------------
extern "C" void kernel_launch(void* const* d_in, const int* in_sizes, int n_in,
                              void* d_out, int out_size, void* d_ws,
                              size_t ws_size, hipStream_t stream) {
  const float* x = (const float*)d_in[0];
  const float* w_qkv = (const float*)d_in[1];
  const float* b_qkv = (const float*)d_in[2];
  const float* w_proj = (const float*)d_in[3];
  const float* b_proj = (const float*)d_in[4];
  const float* mw1 = (const float*)d_in[5];
  const float* mb1 = (const float*)d_in[6];
  const float* mw2 = (const float*)d_in[7];
  const float* mb2 = (const float*)d_in[8];
  const float* tau = (const float*)d_in[9];
  float* out = (float*)d_out;

  const size_t NEEDED = (size_t)(TBL * NH + NH) * 4 + (size_t)65536 * 2 +
                        (size_t)256 * NH * Tt * HD * 2;
  if (ws_size < NEEDED) return;

  float* table = (float*)d_ws;
  float* tablemax = table + TBL * NH;
  f16* wpf = (f16*)(tablemax + NH);
  f16* attnH = wpf + 65536;

  // Stash f16 intermediates in d_out (64 MB fp32): xt = 33.5 MB, wqf = 384 KB.
  // proj_gemm fully overwrites d_out afterwards (stream-ordered).
  f16* xt = (f16*)d_out;
  f16* wqf = (f16*)d_out + (size_t)256 * 65536;

  stage0_kernel<<<4160, 256, 0, stream>>>(x, xt, mw1, mb1, mw2, mb2, w_proj,
                                          w_qkv, table, tablemax, wpf, wqf);
  fused_attn<<<256 * NH, 512, 0, stream>>>(xt, wqf, b_qkv, table, tablemax,
                                           tau, attnH);
  dim3 g3(512, 2);
  proj_gemm<<<g3, 256, 0, stream>>>(attnH, wpf, b_proj, out);
}